// Round 9
// baseline (2458.011 us; speedup 1.0000x reference)
//
#include <hip/hip_runtime.h>

typedef unsigned short u16;
typedef unsigned long long u64;
using short8 = __attribute__((ext_vector_type(8))) short;
using f32x4  = __attribute__((ext_vector_type(4))) float;
using u32x8  = __attribute__((ext_vector_type(8))) unsigned;

#define GF_RELU  1
#define GF_F32   2
#define GF_XPOSE 4

__device__ __forceinline__ float b2f(u16 x) {
    unsigned u = ((unsigned)x) << 16;
    return __builtin_bit_cast(float, u);
}
__device__ __forceinline__ u16 f2b(float f) {
    unsigned u = __builtin_bit_cast(unsigned, f);
    unsigned r = u + 0x7FFFu + ((u >> 16) & 1u);
    return (u16)(r >> 16);
}
__device__ __forceinline__ f32x4 mfma_bf16(uint4 a, uint4 b, f32x4 c) {
    return __builtin_amdgcn_mfma_f32_16x16x32_bf16(
        __builtin_bit_cast(short8, a), __builtin_bit_cast(short8, b), c, 0, 0, 0);
}
__device__ __forceinline__ f32x4 zero4() { f32x4 z = {0.f, 0.f, 0.f, 0.f}; return z; }

// ---------------------------------------------------------------------------
// f32 -> bf16 conversion (grid-stride)
// ---------------------------------------------------------------------------
__global__ __launch_bounds__(256) void cvt_bf16(const float* __restrict__ src,
                                                u16* __restrict__ dst, int n) {
    for (int i = blockIdx.x * 256 + threadIdx.x; i < n; i += gridDim.x * 256)
        dst[i] = f2b(src[i]);
}

// ---------------------------------------------------------------------------
// Pack W_hh / W_ih (f32 in) into unit-major gate order bf16: packed row
// p = unit*4+gate maps to original row gate*512+unit. biasP (f32) = b_ih+b_hh.
// ---------------------------------------------------------------------------
__global__ void pack_params(const float* __restrict__ Whh, const float* __restrict__ Wih,
                            const float* __restrict__ bih, const float* __restrict__ bhh,
                            u16* __restrict__ WhhP, u16* __restrict__ WihP,
                            float* __restrict__ biasP) {
    int p = blockIdx.x;      // 2048
    int t = threadIdx.x;     // 256
    int orig = ((p & 3) << 9) + (p >> 2);
    WhhP[((long)p << 9) + t]       = f2b(Whh[((long)orig << 9) + t]);
    WhhP[((long)p << 9) + 256 + t] = f2b(Whh[((long)orig << 9) + 256 + t]);
    WihP[((long)p << 8) + t]       = f2b(Wih[((long)orig << 8) + t]);
    if (t == 0) biasP[p] = bih[orig] + bhh[orig];
}

// ---------------------------------------------------------------------------
// Generic C = act(A @ B^T + bias) GEMM, 64x128 tile, register-prefetch
// pipeline. bf16 in, bf16/f32 out. A row-stride = ksplit; k >= ksplit reads
// A2. GF_XPOSE: x_proj time-major.
// ---------------------------------------------------------------------------
__global__ __launch_bounds__(256) void gemm_bt(
    const u16* __restrict__ A, const u16* __restrict__ A2, int ksplit,
    const u16* __restrict__ B, void* __restrict__ Cout,
    int M, int N, int K,
    long sAb, long sBb, long sCb,
    const float* __restrict__ bias, const float* __restrict__ rowmask, int flags) {
    __shared__ __align__(16) u16 As[64][40];
    __shared__ __align__(16) u16 Bs[128][40];
    const int bz = blockIdx.z;
    const u16* Ab = A + (long)bz * sAb;
    const u16* Bb = B + (long)bz * sBb;
    const int m0 = blockIdx.x << 6, n0 = blockIdx.y << 7;
    const int tid = threadIdx.x;
    const int lane = tid & 63, wave = tid >> 6;
    const int srow = tid >> 2, skc = (tid & 3) << 3;
    const int frm = lane & 15, fq = lane >> 4;

    auto loadA = [&](int ka) -> uint4 {
        const u16* p = (ka < ksplit)
            ? Ab + (long)(m0 + srow) * ksplit + ka
            : A2 + (long)(m0 + srow) * (K - ksplit) + (ka - ksplit);
        return *(const uint4*)p;
    };
    const u16* Brow0 = Bb + (long)(n0 + srow) * K;
    const u16* Brow1 = Bb + (long)(n0 + 64 + srow) * K;

    f32x4 acc[8];
#pragma unroll
    for (int i = 0; i < 8; i++) acc[i] = zero4();

    uint4 a  = loadA(skc);
    uint4 b0 = *(const uint4*)(Brow0 + skc);
    uint4 b1 = *(const uint4*)(Brow1 + skc);

    for (int k0 = 0; k0 < K; k0 += 32) {
        __syncthreads();
        *(uint4*)&As[srow][skc] = a;
        *(uint4*)&Bs[srow][skc] = b0;
        *(uint4*)&Bs[64 + srow][skc] = b1;
        __syncthreads();
        int kn = k0 + 32;
        if (kn < K) {           // prefetch next tile; overlaps MFMAs below
            a  = loadA(kn + skc);
            b0 = *(const uint4*)(Brow0 + kn + skc);
            b1 = *(const uint4*)(Brow1 + kn + skc);
        }
        uint4 af = *(const uint4*)&As[(wave << 4) + frm][fq << 3];
#pragma unroll
        for (int nt = 0; nt < 8; nt++) {
            uint4 bf = *(const uint4*)&Bs[(nt << 4) + frm][fq << 3];
            acc[nt] = mfma_bf16(af, bf, acc[nt]);
        }
    }
#pragma unroll
    for (int nt = 0; nt < 8; nt++) {
        int col = n0 + (nt << 4) + frm;
        float bv = bias ? bias[col] : 0.f;
#pragma unroll
        for (int r = 0; r < 4; r++) {
            int row = m0 + (wave << 4) + (fq << 2) + r;
            float v = acc[nt][r] + bv;
            if (flags & GF_RELU) v = fmaxf(v, 0.f);
            if (rowmask) v *= rowmask[row];
            long orow = (flags & GF_XPOSE) ? (long)((row & 1023) * 8 + (row >> 10))
                                           : (long)row;
            if (flags & GF_F32)
                ((float*)Cout)[(long)bz * sCb + orow * N + col] = v;
            else
                ((u16*)Cout)[(long)bz * sCb + orow * N + col] = f2b(v);
        }
    }
}

// ---------------------------------------------------------------------------
// LSTM recurrence loop. r6: atomics execute at the MALL (WRITE_SIZE 266MB),
// so all prior variants paid ~2 MALL legs/step. Fast path (L2C=true, group
// verified on ONE XCD) uses the only intra-XCD coherent route:
//   publish : plain stores (write-through L1 -> local L2); per-wave vmcnt
//             drain via __syncthreads; then one plain per-WG tag dword.
//   detect  : wave0 polls the 8 tags via s_dcache_inv + s_load (scalar K$
//             reads through L2 -> coherent, ~200cy/round). Tag base forced
//             into SGPRs via readfirstlane (r7 compile fix).
//   payload : wave0 first-touch plain vector load of the MONOTONE RING slot
//             (fresh addresses each step -> guaranteed L1 miss -> L2 fill);
//             embedded tag verified before use.
//   backstop: publisher ALSO mirrors each atom via sc0 sc1 (MALL) after the
//             tag release (off critical path, same value) -> the MALL
//             re-read loop always terminates even if the L2 assumption
//             fails. Fast path can never consume garbage NOR hang.
// L2C=false: r3-proven MALL path (sc0 sc1 both sides) on the same ring,
// wave0-polls + LDS broadcast. Ring aliases w (16MB), tags alias scores --
// both written only AFTER lstm_rec; inter-dispatch L2 WB/INV makes the
// aliasing safe. Zero workspace growth.
// Liveness audit (r8): per-iteration __syncthreads is UNCONDITIONAL; all
// spin loops budget-bounded with wave-uniform exits; 64 WGs co-resident.
// ---------------------------------------------------------------------------
template<bool L2C>
__device__ __forceinline__ void lstm_loop(
    const u16* __restrict__ xproj, u16* __restrict__ h,
    u64* __restrict__ ring, unsigned* __restrict__ tags,
    const uint4 (&bfrag)[2][16], unsigned* hsh, int* hflag,
    int g, int s, int wv, int lane, int frm, int fq, int colbase, int tid) {
    float creg = 0.f;                     // cell state (batch g, unit s*64+wv*8+lane), lanes 0..7
    int budget = 1 << 20;                 // poll bailout: guarantees termination

#pragma unroll 1
    for (int t = 0; t < 1024; t++) {
        // prefetch x_proj for this step (time-major layout) -- overlaps poll
        float xp0 = b2f(xproj[((long)(t * 8 + g) << 11) + colbase + frm]);
        float xp1 = b2f(xproj[((long)(t * 8 + g) << 11) + colbase + 16 + frm]);

        float s0, s1;
        if (t > 0) {
            const unsigned want = (unsigned)t;
            const u64* slot = ring + (((long)((g << 10) + (t - 1))) << 8);
            if (wv == 0) {
                if constexpr (L2C) {
                    // coherent scalar poll of the 8 WG tags (L2 latency)
                    const unsigned* tbase = tags + (((g << 10) + (t - 1)) << 3);
                    u64 ta = (u64)tbase;
                    unsigned tlo = __builtin_amdgcn_readfirstlane((unsigned)ta);
                    unsigned thi = __builtin_amdgcn_readfirstlane((unsigned)(ta >> 32));
                    u64 tsg = ((u64)thi << 32) | tlo;
                    while (true) {
                        u32x8 tg;
                        asm volatile(
                            "s_dcache_inv\n\t"
                            "s_waitcnt lgkmcnt(0)\n\t"
                            "s_load_dwordx8 %0, %1, 0\n\t"
                            "s_waitcnt lgkmcnt(0)"
                            : "=s"(tg) : "s"(tsg) : "memory");
                        bool ok = (tg[0] == want) & (tg[1] == want) &
                                  (tg[2] == want) & (tg[3] == want) &
                                  (tg[4] == want) & (tg[5] == want) &
                                  (tg[6] == want) & (tg[7] == want);
                        if (ok || --budget < 0) break;
                    }
                }
                const u64* p0 = slot + lane;
                const u64* p1 = slot + 64 + lane;
                const u64* p2 = slot + 128 + lane;
                const u64* p3 = slot + 192 + lane;
                u64 v0, v1, v2, v3;
                bool need_mall = true;
                if constexpr (L2C) {
                    // first-touch plain loads (slot never seen by this L1)
                    v0 = p0[0]; v1 = p1[0]; v2 = p2[0]; v3 = p3[0];
                    bool ok = ((unsigned)(v0 >> 32) == want) &
                              ((unsigned)(v1 >> 32) == want) &
                              ((unsigned)(v2 >> 32) == want) &
                              ((unsigned)(v3 >> 32) == want);
                    need_mall = !__all(ok);
                }
                if (need_mall) {
                    // backstop / fallback: MALL tag-in-data poll (r3-proven);
                    // mirror stores guarantee termination in fast path too
                    while (true) {
                        asm volatile(
                            "global_load_dwordx2 %0, %4, off sc0 sc1\n\t"
                            "global_load_dwordx2 %1, %5, off sc0 sc1\n\t"
                            "global_load_dwordx2 %2, %6, off sc0 sc1\n\t"
                            "global_load_dwordx2 %3, %7, off sc0 sc1\n\t"
                            "s_waitcnt vmcnt(0)"
                            : "=&v"(v0), "=&v"(v1), "=&v"(v2), "=&v"(v3)
                            : "v"(p0), "v"(p1), "v"(p2), "v"(p3)
                            : "memory");
                        bool ok = ((unsigned)(v0 >> 32) == want) &
                                  ((unsigned)(v1 >> 32) == want) &
                                  ((unsigned)(v2 >> 32) == want) &
                                  ((unsigned)(v3 >> 32) == want);
                        if (__all(ok) || --budget < 0) break;
                    }
                }
                hsh[lane]       = (unsigned)v0;
                hsh[64 + lane]  = (unsigned)v1;
                hsh[128 + lane] = (unsigned)v2;
                hsh[192 + lane] = (unsigned)v3;
                __threadfence_block();        // LDS payload before flag
                if (lane == 0)
                    __hip_atomic_store(hflag, t, __ATOMIC_RELAXED,
                                       __HIP_MEMORY_SCOPE_WORKGROUP);
            } else {
                // waves 1-7: spin on LDS flag (no fabric traffic)
                while (__hip_atomic_load(hflag, __ATOMIC_RELAXED,
                                         __HIP_MEMORY_SCOPE_WORKGROUP) < t) {
                    if (--budget < 0) break;
                }
                __threadfence_block();        // flag before payload reads
            }

            f32x4 a0p[4], a1p[4];
#pragma unroll
            for (int r = 0; r < 4; r++) { a0p[r] = zero4(); a1p[r] = zero4(); }
#pragma unroll
            for (int r4 = 0; r4 < 4; r4++) {
                uint4 af[4];
#pragma unroll
                for (int q = 0; q < 4; q++)
                    af[q] = *(const uint4*)&hsh[(((r4 << 2) | q) << 4) + (fq << 2)];
#pragma unroll
                for (int q = 0; q < 4; q++) {
                    a0p[r4] = mfma_bf16(af[q], bfrag[0][(r4 << 2) | q], a0p[r4]);
                    a1p[r4] = mfma_bf16(af[q], bfrag[1][(r4 << 2) | q], a1p[r4]);
                }
            }
            // A-rows are broadcast-identical -> row-0 result valid on ALL lanes
            s0 = (a0p[0][0] + a0p[1][0]) + (a0p[2][0] + a0p[3][0]) + xp0;
            s1 = (a1p[0][0] + a1p[1][0]) + (a1p[2][0] + a1p[3][0]) + xp1;
        } else {
            s0 = xp0;                     // h(-1) = 0
            s1 = xp1;
        }

        // gate gather: lane j (<8) needs cols 4j..4j+3 of this wave's 32 cols.
        // cols 0..15 live in s0 (lane = col&15), 16..31 in s1.
        float ss[4];
#pragma unroll
        for (int k = 0; k < 4; k++) {
            int src = ((lane << 2) + k) & 15;
            float t0 = __shfl(s0, src);
            float t1 = __shfl(s1, src);
            ss[k] = (lane < 4) ? t0 : t1;
        }
        float iv = 1.f / (1.f + __expf(-ss[0]));
        float fv = 1.f / (1.f + __expf(-ss[1]));
        float gv = 1.f - 2.f / (__expf(2.f * ss[2]) + 1.f);
        float ov = 1.f / (1.f + __expf(-ss[3]));
        creg = fv * creg + iv * gv;
        float hv = ov * (1.f - 2.f / (__expf(2.f * creg) + 1.f));
        float hn = __shfl_down(hv, 1);    // neighbor unit's h

        const bool pub = (lane < 8) && !(lane & 1);
        u64 pv = 0; u64* dst = nullptr;
        if (pub) {
            unsigned dw = (unsigned)f2b(hv) | ((unsigned)f2b(hn) << 16);
            int d = (s << 5) + (wv << 2) + (lane >> 1);   // group h dword 0..255
            pv = ((u64)(unsigned)(t + 1) << 32) | (u64)dw;
            dst = ring + (((long)((g << 10) + t)) << 8) + d;
            if constexpr (L2C) {
                *dst = pv;                // plain store: write-through L1 -> L2
            } else {
                asm volatile("global_store_dwordx2 %0, %1, off sc0 sc1"
                             :: "v"(dst), "v"(pv) : "memory");
            }
            ((unsigned*)h)[(((long)(g * 1024 + t)) << 8) + d] = dw;
        }
        if constexpr (L2C) {
            __syncthreads();              // drains vmcnt -> payload in L2
            if (tid == 0)
                tags[(((g << 10) + t) << 3) + s] = (unsigned)(t + 1);
            if (pub)                      // MALL mirror: backstop liveness,
                asm volatile("global_store_dwordx2 %0, %1, off sc0 sc1"
                             :: "v"(dst), "v"(pv) : "memory");   // off crit path
        }
    }
}

// ---------------------------------------------------------------------------
// Persistent LSTM recurrence, batch-partitioned: 64 WGs = 8 groups x 8 WGs.
// Group g = bid%8 owns batch g; slice s = bid/8 owns packed gate-cols
// [s*256,+256); wave wv owns 32 cols = units [s*64+wv*8,+8). Weights:
// bfrag[2][16] = 128 VGPRs/lane (proven max). Startup XCD placement check
// (r4-proven, r6 confirmed it engages): MALL-published XCC_IDs, unanimous
// verdict. Same-XCD -> write-through-L2 + scalar-poll fast path; else
// MALL path. Wrong placement degrades speed only, never correctness.
// ---------------------------------------------------------------------------
__global__ __launch_bounds__(512, 1) void lstm_rec(
    const u16* __restrict__ WhhP, const u16* __restrict__ xproj,
    u16* __restrict__ h, u64* __restrict__ ring, unsigned* __restrict__ tags,
    unsigned* __restrict__ xcdid) {
    __shared__ __align__(16) unsigned hshare[256];   // group h payload (dwords)
    __shared__ int hflag;                            // last staged step
    const int bid = blockIdx.x;           // 64
    const int g = bid & 7;                // batch / group
    const int s = bid >> 3;               // gate-col slice 0..7
    const int tid = threadIdx.x;          // 512
    const int lane = tid & 63, wv = tid >> 6;
    const int frm = lane & 15, fq = lane >> 4;
    const int colbase = (s << 8) + (wv << 5);   // global packed gate-col base

    uint4 bfrag[2][16];
#pragma unroll
    for (int T = 0; T < 2; T++)
#pragma unroll
        for (int kk = 0; kk < 16; kk++)
            bfrag[T][kk] = *(const uint4*)&WhhP[((long)(colbase + (T << 4) + frm) << 9) +
                                                (kk << 5) + (fq << 3)];

    // ---- one-time XCD placement check (MALL-coherent, deterministic) ----
    unsigned myxcd;
    asm volatile("s_getreg_b32 %0, hwreg(HW_REG_XCC_ID)" : "=s"(myxcd));
    if (tid == 0) {
        hflag = -1;
        unsigned val = 0x100u | (myxcd & 0xffu);
        asm volatile("global_store_dword %0, %1, off sc0 sc1"
                     :: "v"(&xcdid[bid]), "v"(val) : "memory");
    }
    const unsigned* pid = &xcdid[g + ((lane & 7) << 3)];   // group member g+8j
    unsigned idv = 0;
    int bd = 1 << 22;
    while (true) {
        asm volatile("global_load_dword %0, %1, off sc0 sc1\n\ts_waitcnt vmcnt(0)"
                     : "=&v"(idv) : "v"(pid) : "memory");
        if (__all((idv >> 8) == 1u) || --bd < 0) break;
    }
    bool same = (bd >= 0) && __all((idv & 0xffu) == (__shfl(idv, 0) & 0xffu));
    __syncthreads();                      // hflag init visible to all waves

    if (same)
        lstm_loop<true>(xproj, h, ring, tags, bfrag, hshare, &hflag,
                        g, s, wv, lane, frm, fq, colbase, tid);
    else
        lstm_loop<false>(xproj, h, ring, tags, bfrag, hshare, &hflag,
                         g, s, wv, lane, frm, fq, colbase, tid);
}

// ---------------------------------------------------------------------------
// h [b][t][u] -> hT [b][u][t]
// ---------------------------------------------------------------------------
__global__ __launch_bounds__(256) void transpose_h(const u16* __restrict__ h,
                                                   u16* __restrict__ hT) {
    __shared__ __align__(16) u16 tile[64][72];
    const int b = blockIdx.z;
    const int t0 = blockIdx.x << 6, u0 = blockIdx.y << 6;
    const int tid = threadIdx.x;
    const int r = tid >> 3, c8 = (tid & 7) << 3;
#pragma unroll
    for (int j = 0; j < 2; j++) {
        int row = r + (j << 5);
        *(uint4*)&tile[row][c8] =
            *(const uint4*)&h[(((long)b << 10) + t0 + row) * 512 + u0 + c8];
    }
    __syncthreads();
#pragma unroll
    for (int j = 0; j < 2; j++) {
        int urow = r + (j << 5);
        unsigned wds[4];
#pragma unroll
        for (int k = 0; k < 4; k++) {
            unsigned lo = tile[c8 + (k << 1)][urow];
            unsigned hi = tile[c8 + (k << 1) + 1][urow];
            wds[k] = lo | (hi << 16);
        }
        uint4 v; v.x = wds[0]; v.y = wds[1]; v.z = wds[2]; v.w = wds[3];
        *(uint4*)&hT[(((long)b << 9) + u0 + urow) * 1024 + t0 + c8] = v;
    }
}

// ---------------------------------------------------------------------------
// Masked softmax over rows of scores [8192][1024]; w = softmax*mask (bf16);
// hasnb = 1.0 if any neighbor else 0.0
// ---------------------------------------------------------------------------
__global__ __launch_bounds__(256) void softmax_row(
    const float* __restrict__ scores, const int* __restrict__ adj,
    u16* __restrict__ w, float* __restrict__ hasnb) {
    __shared__ float red[4];
    const int row = blockIdx.x;  // 8192
    const int i = row & 1023;
    const int tid = threadIdx.x;
    const int lane = tid & 63, wave = tid >> 6;
    const float* s = scores + ((long)row << 10);
    const int* arow = adj + ((long)row << 10);

    float sv[4]; bool mk[4];
    float mx = -3.0e38f;
#pragma unroll
    for (int q = 0; q < 4; q++) {
        int j = tid + (q << 8);
        mk[q] = (arow[j] > 0) && (j != i);
        sv[q] = s[j];
        if (mk[q]) mx = fmaxf(mx, sv[q]);
    }
    for (int off = 32; off; off >>= 1) mx = fmaxf(mx, __shfl_xor(mx, off));
    if (lane == 0) red[wave] = mx;
    __syncthreads();
    mx = fmaxf(fmaxf(red[0], red[1]), fmaxf(red[2], red[3]));
    float e[4]; float sum = 0.f;
#pragma unroll
    for (int q = 0; q < 4; q++) {
        e[q] = mk[q] ? __expf(sv[q] - mx) : 0.f;
        sum += e[q];
    }
    __syncthreads();
    for (int off = 32; off; off >>= 1) sum += __shfl_xor(sum, off);
    if (lane == 0) red[wave] = sum;
    __syncthreads();
    sum = red[0] + red[1] + red[2] + red[3];
    float inv = sum > 0.f ? 1.f / sum : 0.f;
#pragma unroll
    for (int q = 0; q < 4; q++) {
        int j = tid + (q << 8);
        w[((long)row << 10) + j] = f2b(e[q] * inv);
    }
    if (tid == 0) hasnb[row] = sum > 0.f ? 1.f : 0.f;
}

// ---------------------------------------------------------------------------
extern "C" void kernel_launch(void* const* d_in, const int* in_sizes, int n_in,
                              void* d_out, int out_size, void* d_ws, size_t ws_size,
                              hipStream_t stream) {
    const float* feats = (const float*)d_in[0];
    const int*   adj   = (const int*)d_in[1];
    const float* W_ih  = (const float*)d_in[2];
    const float* W_hh  = (const float*)d_in[3];
    const float* b_ih  = (const float*)d_in[4];
    const float* b_hh  = (const float*)d_in[5];
    const float* gx_W1 = (const float*)d_in[6];  const float* gx_b1 = (const float*)d_in[7];
    const float* gx_W2 = (const float*)d_in[8];  const float* gx_b2 = (const float*)d_in[9];
    const float* gz_W1 = (const float*)d_in[10]; const float* gz_b1 = (const float*)d_in[11];
    const float* gz_W2 = (const float*)d_in[12]; const float* gz_b2 = (const float*)d_in[13];
    const float* gv_W1 = (const float*)d_in[14]; const float* gv_b1 = (const float*)d_in[15];
    const float* gv_W2 = (const float*)d_in[16]; const float* gv_b2 = (const float*)d_in[17];
    const float* gn_W1 = (const float*)d_in[18]; const float* gn_b1 = (const float*)d_in[19];
    const float* gn_W2 = (const float*)d_in[20]; const float* gn_b2 = (const float*)d_in[21];
    const float* out_W = (const float*)d_in[22]; const float* out_b = (const float*)d_in[23];

    char* ws = (char*)d_ws;
    size_t off = 0;
    auto alloc = [&](size_t bytes) {
        void* p = ws + off;
        off += (bytes + 255) & ~(size_t)255;
        return p;
    };
    u16* WhhP      = (u16*)alloc(2048L * 512 * 2);
    u16* WihP      = (u16*)alloc(2048L * 256 * 2);
    float* biasP   = (float*)alloc(2048L * 4);
    unsigned* xcdid = (unsigned*)alloc(64L * 4);
    u16* featsB    = (u16*)alloc(8192L * 256 * 2);
    u16* gxW1b     = (u16*)alloc(256L * 512 * 2);
    u16* gxW2b     = (u16*)alloc(256L * 256 * 2);
    u16* gvW1b     = (u16*)alloc(256L * 512 * 2);
    u16* gvW2b     = (u16*)alloc(256L * 256 * 2);
    u16* gzW1b     = (u16*)alloc(256L * 512 * 2);
    u16* gzW2b     = (u16*)alloc(256L * 256 * 2);
    u16* gnW1b     = (u16*)alloc(256L * 256 * 2);
    u16* gnW2b     = (u16*)alloc(256L * 256 * 2);
    u16* outWb     = (u16*)alloc(256L * 768 * 2);
    u16* xproj     = (u16*)alloc(8L * 1024 * 2048 * 2);
    u16* h         = (u16*)alloc(8L * 1024 * 512 * 2);
    u16* hT        = (u16*)alloc(8L * 1024 * 512 * 2);
    u16* t1        = (u16*)alloc(8192L * 256 * 2);
    u16* tB        = (u16*)alloc(8192L * 256 * 2);
    u16* ax        = (u16*)alloc(8192L * 256 * 2);
    u16* av        = (u16*)alloc(8192L * 256 * 2);
    u16* agg       = (u16*)alloc(8192L * 256 * 2);
    float* hasnb   = (float*)alloc(8192L * 4);
    float* scores  = (float*)alloc(8L * 1024 * 1024 * 4);
    u16* w         = (u16*)alloc(8L * 1024 * 1024 * 2);
    if (off > ws_size) return;  // workspace too small -> fail visibly

    // Exchange buffers ALIAS later-written memory (zero workspace growth):
    // ring (8 groups x 1024 steps x 256 u64 = 16MB) aliases w (written only
    // by softmax, after lstm_rec). tags (8x1024x8 u32 = 256KB) alias scores
    // (written by the scores GEMM, after lstm_rec). Inter-dispatch L2
    // writeback/invalidate makes cross-kernel aliasing safe.
    u64* ring      = (u64*)w;
    unsigned* tags = (unsigned*)scores;

    (void)hipMemsetAsync(tags, 0, 8L * 1024 * 8 * 4, stream);  // tag slots 0
    (void)hipMemsetAsync(xcdid, 0, 64L * 4, stream);           // placement slots
    pack_params<<<2048, 256, 0, stream>>>(W_hh, W_ih, b_ih, b_hh, WhhP, WihP, biasP);

    auto cvt = [&](const float* src, u16* dst, int n) {
        cvt_bf16<<<(n + 1023) / 1024, 256, 0, stream>>>(src, dst, n);
    };
    cvt(feats, featsB, 8192 * 256);
    cvt(gx_W1, gxW1b, 256 * 512);  cvt(gx_W2, gxW2b, 256 * 256);
    cvt(gv_W1, gvW1b, 256 * 512);  cvt(gv_W2, gvW2b, 256 * 256);
    cvt(gz_W1, gzW1b, 256 * 512);  cvt(gz_W2, gzW2b, 256 * 256);
    cvt(gn_W1, gnW1b, 256 * 256);  cvt(gn_W2, gnW2b, 256 * 256);
    cvt(out_W, outWb, 256 * 768);

    // x_proj = feats @ W_ihP^T + (b_ih+b_hh), stored time-major [t][b][p]
    gemm_bt<<<dim3(128, 16, 1), 256, 0, stream>>>(
        featsB, nullptr, 256, WihP, xproj, 8192, 2048, 256, 0, 0, 0,
        biasP, nullptr, GF_XPOSE);

    lstm_rec<<<64, 512, 0, stream>>>(WhhP, xproj, h, ring, tags, xcdid);

    transpose_h<<<dim3(16, 8, 8), 256, 0, stream>>>(h, hT);

    // ax = mlp(h; gx)
    gemm_bt<<<dim3(128, 2, 1), 256, 0, stream>>>(
        h, nullptr, 512, gxW1b, t1, 8192, 256, 512, 0, 0, 0, gx_b1, nullptr, GF_RELU);
    gemm_bt<<<dim3(128, 2, 1), 256, 0, stream>>>(
        t1, nullptr, 256, gxW2b, ax, 8192, 256, 256, 0, 0, 0, gx_b2, nullptr, 0);
    // av = mlp(h; gv)
    gemm_bt<<<dim3(128, 2, 1), 256, 0, stream>>>(
        h, nullptr, 512, gvW1b, t1, 8192, 256, 512, 0, 0, 0, gv_b1, nullptr, GF_RELU);
    gemm_bt<<<dim3(128, 2, 1), 256, 0, stream>>>(
        t1, nullptr, 256, gvW2b, av, 8192, 256, 256, 0, 0, 0, gv_b2, nullptr, 0);

    // scores[b] = ax[b] @ av[b]^T  (f32)
    gemm_bt<<<dim3(16, 8, 8), 256, 0, stream>>>(
        ax, nullptr, 256, av, scores, 1024, 1024, 256,
        262144, 262144, 1048576, nullptr, nullptr, GF_F32);

    softmax_row<<<8192, 256, 0, stream>>>(scores, adj, w, hasnb);

    // sagg[b] = w[b] @ h[b]  via A=w, B=hT (B^T form); xproj is dead -> reuse
    u16* sagg = xproj;
    gemm_bt<<<dim3(16, 4, 8), 256, 0, stream>>>(
        w, nullptr, 1024, hT, sagg, 1024, 512, 1024,
        1048576, 524288, 524288, nullptr, nullptr, 0);

    // agg = mlp(mlp(sagg; gz); gn) * hasnb
    gemm_bt<<<dim3(128, 2, 1), 256, 0, stream>>>(
        sagg, nullptr, 512, gzW1b, t1, 8192, 256, 512, 0, 0, 0, gz_b1, nullptr, GF_RELU);
    gemm_bt<<<dim3(128, 2, 1), 256, 0, stream>>>(
        t1, nullptr, 256, gzW2b, tB, 8192, 256, 256, 0, 0, 0, gz_b2, nullptr, 0);
    gemm_bt<<<dim3(128, 2, 1), 256, 0, stream>>>(
        tB, nullptr, 256, gnW1b, t1, 8192, 256, 256, 0, 0, 0, gn_b1, nullptr, GF_RELU);
    gemm_bt<<<dim3(128, 2, 1), 256, 0, stream>>>(
        t1, nullptr, 256, gnW2b, agg, 8192, 256, 256, 0, 0, 0, gn_b2, hasnb, 0);

    // out = concat(h, agg) @ out_W^T + out_b  (f32 output)
    gemm_bt<<<dim3(128, 2, 1), 256, 0, stream>>>(
        h, agg, 512, outWb, (float*)d_out, 8192, 256, 768, 0, 0, 0, out_b, nullptr, GF_F32);
}

// Round 10
// 2388.280 us; speedup vs baseline: 1.0292x; 1.0292x over previous
//
#include <hip/hip_runtime.h>

typedef unsigned short u16;
typedef unsigned long long u64;
using short8 = __attribute__((ext_vector_type(8))) short;
using f32x4  = __attribute__((ext_vector_type(4))) float;

#define GF_RELU  1
#define GF_F32   2
#define GF_XPOSE 4
#define GF_BIASB 8

__device__ __forceinline__ float b2f(u16 x) {
    unsigned u = ((unsigned)x) << 16;
    return __builtin_bit_cast(float, u);
}
__device__ __forceinline__ u16 f2b(float f) {
    unsigned u = __builtin_bit_cast(unsigned, f);
    unsigned r = u + 0x7FFFu + ((u >> 16) & 1u);
    return (u16)(r >> 16);
}
__device__ __forceinline__ f32x4 mfma_bf16(uint4 a, uint4 b, f32x4 c) {
    return __builtin_amdgcn_mfma_f32_16x16x32_bf16(
        __builtin_bit_cast(short8, a), __builtin_bit_cast(short8, b), c, 0, 0, 0);
}
__device__ __forceinline__ f32x4 zero4() { f32x4 z = {0.f, 0.f, 0.f, 0.f}; return z; }

// ---------------------------------------------------------------------------
// Fused f32 -> bf16 conversion for up to 10 buffers in ONE launch (replaces
// 10 cvt launches). Each block handles 1024 elements of its job.
// ---------------------------------------------------------------------------
struct CvtJobs {
    const float* src[10];
    u16* dst[10];
    int n[10];
    int off[10];   // starting block of job j
    int cnt;
};
__global__ __launch_bounds__(256) void cvt_multi(CvtJobs J) {
    int b = blockIdx.x;
    int j = J.cnt - 1;
    for (int k = 1; k < J.cnt; ++k)
        if (b < J.off[k]) { j = k - 1; break; }
    const float* s = J.src[j];
    u16* d = J.dst[j];
    int n = J.n[j];
    int e0 = (b - J.off[j]) << 10;
#pragma unroll
    for (int k = 0; k < 4; ++k) {
        int i = e0 + (k << 8) + threadIdx.x;
        if (i < n) d[i] = f2b(s[i]);
    }
}

// ---------------------------------------------------------------------------
// Concat biases: cat1 = [a1;b1], cat2 = [a2;b2] (256 f32 each half). 1 launch.
// ---------------------------------------------------------------------------
__global__ __launch_bounds__(512) void bias_pack(
    const float* __restrict__ a1, const float* __restrict__ b1,
    const float* __restrict__ a2, const float* __restrict__ b2,
    float* __restrict__ cat1, float* __restrict__ cat2) {
    int t = threadIdx.x;
    if (t < 256) { cat1[t] = a1[t]; cat2[t] = a2[t]; }
    else         { cat1[t] = b1[t - 256]; cat2[t] = b2[t - 256]; }
}

// ---------------------------------------------------------------------------
// Pack W_hh / W_ih (f32 in) into unit-major gate order bf16: packed row
// p = unit*4+gate maps to original row gate*512+unit. biasP (f32) = b_ih+b_hh.
// ---------------------------------------------------------------------------
__global__ void pack_params(const float* __restrict__ Whh, const float* __restrict__ Wih,
                            const float* __restrict__ bih, const float* __restrict__ bhh,
                            u16* __restrict__ WhhP, u16* __restrict__ WihP,
                            float* __restrict__ biasP) {
    int p = blockIdx.x;      // 2048
    int t = threadIdx.x;     // 256
    int orig = ((p & 3) << 9) + (p >> 2);
    WhhP[((long)p << 9) + t]       = f2b(Whh[((long)orig << 9) + t]);
    WhhP[((long)p << 9) + 256 + t] = f2b(Whh[((long)orig << 9) + 256 + t]);
    WihP[((long)p << 8) + t]       = f2b(Wih[((long)orig << 8) + t]);
    if (t == 0) biasP[p] = bih[orig] + bhh[orig];
}

// ---------------------------------------------------------------------------
// Generic C = act(A @ B^T + bias) GEMM, 64x128 tile, register-prefetch
// pipeline. bf16 in, bf16/f32 out. ksplit doubles as the A row-stride; for
// k >= ksplit reads A2 (concat). GF_XPOSE: x_proj time-major output.
// GF_BIASB: bias indexed per-batch (bias[bz*N + col]) for batched GEMMs.
// ---------------------------------------------------------------------------
__global__ __launch_bounds__(256) void gemm_bt(
    const u16* __restrict__ A, const u16* __restrict__ A2, int ksplit,
    const u16* __restrict__ B, void* __restrict__ Cout,
    int M, int N, int K,
    long sAb, long sBb, long sCb,
    const float* __restrict__ bias, const float* __restrict__ rowmask, int flags) {
    __shared__ __align__(16) u16 As[64][40];
    __shared__ __align__(16) u16 Bs[128][40];
    const int bz = blockIdx.z;
    const u16* Ab = A + (long)bz * sAb;
    const u16* Bb = B + (long)bz * sBb;
    const int m0 = blockIdx.x << 6, n0 = blockIdx.y << 7;
    const int tid = threadIdx.x;
    const int lane = tid & 63, wave = tid >> 6;
    const int srow = tid >> 2, skc = (tid & 3) << 3;
    const int frm = lane & 15, fq = lane >> 4;

    auto loadA = [&](int ka) -> uint4 {
        const u16* p = (ka < ksplit)
            ? Ab + (long)(m0 + srow) * ksplit + ka
            : A2 + (long)(m0 + srow) * (K - ksplit) + (ka - ksplit);
        return *(const uint4*)p;
    };
    const u16* Brow0 = Bb + (long)(n0 + srow) * K;
    const u16* Brow1 = Bb + (long)(n0 + 64 + srow) * K;

    f32x4 acc[8];
#pragma unroll
    for (int i = 0; i < 8; i++) acc[i] = zero4();

    uint4 a  = loadA(skc);
    uint4 b0 = *(const uint4*)(Brow0 + skc);
    uint4 b1 = *(const uint4*)(Brow1 + skc);

    for (int k0 = 0; k0 < K; k0 += 32) {
        __syncthreads();
        *(uint4*)&As[srow][skc] = a;
        *(uint4*)&Bs[srow][skc] = b0;
        *(uint4*)&Bs[64 + srow][skc] = b1;
        __syncthreads();
        int kn = k0 + 32;
        if (kn < K) {           // prefetch next tile; overlaps MFMAs below
            a  = loadA(kn + skc);
            b0 = *(const uint4*)(Brow0 + kn + skc);
            b1 = *(const uint4*)(Brow1 + kn + skc);
        }
        uint4 af = *(const uint4*)&As[(wave << 4) + frm][fq << 3];
#pragma unroll
        for (int nt = 0; nt < 8; nt++) {
            uint4 bf = *(const uint4*)&Bs[(nt << 4) + frm][fq << 3];
            acc[nt] = mfma_bf16(af, bf, acc[nt]);
        }
    }
#pragma unroll
    for (int nt = 0; nt < 8; nt++) {
        int col = n0 + (nt << 4) + frm;
        float bv = 0.f;
        if (bias) bv = (flags & GF_BIASB) ? bias[bz * N + col] : bias[col];
#pragma unroll
        for (int r = 0; r < 4; r++) {
            int row = m0 + (wave << 4) + (fq << 2) + r;
            float v = acc[nt][r] + bv;
            if (flags & GF_RELU) v = fmaxf(v, 0.f);
            if (rowmask) v *= rowmask[row];
            long orow = (flags & GF_XPOSE) ? (long)((row & 1023) * 8 + (row >> 10))
                                           : (long)row;
            if (flags & GF_F32)
                ((float*)Cout)[(long)bz * sCb + orow * N + col] = v;
            else
                ((u16*)Cout)[(long)bz * sCb + orow * N + col] = f2b(v);
        }
    }
}

// ---------------------------------------------------------------------------
// LSTM recurrence loop (r6-proven BEST variant: 2074 us measured).
// L2C=true : group WGs verified on ONE XCD. Exchange via PLAIN (unscoped)
//   atomics. Publish: global_atomic_swap_x2 (fire-and-forget). Poll:
//   global_atomic_add_x2 with 0 + sc0 (atomic-read-old; never stale L1).
// L2C=false: r3-proven MALL path (sc0 sc1 load/store).
// Both paths: ONLY wave 0 of each WG polls the fabric (4 atoms/lane); it
// stages the payload into shared LDS, fences, raises an LDS flag; waves 1-7
// spin on the flag (zero fabric traffic). Safe: wave0's poll for step t+1
// can only succeed after ALL waves of the group published step t, which
// happens after their step-t payload reads -> no hshare overwrite race.
// Protocol: 256 tag-in-data u64 atoms {tag=t+1, dword=2 bf16}, parity
// double-buffered; 8B atomics self-validate, no fences needed on fabric.
// After 9 rounds / 8 exchange mechanisms, the ~2.0-2.1us/step is the
// structural floor of cross-WG recurrence on this part -- do not re-litigate
// signaling; remaining optimization lives in the non-lstm tail.
// ---------------------------------------------------------------------------
template<bool L2C>
__device__ __forceinline__ void lstm_loop(
    const u16* __restrict__ xproj, u16* __restrict__ h, u64* __restrict__ hx,
    const uint4 (&bfrag)[2][16], unsigned* hsh, int* hflag,
    int g, int s, int wv, int lane, int frm, int fq, int colbase) {
    float creg = 0.f;                     // cell state (batch g, unit s*64+wv*8+lane), lanes 0..7
    int budget = 1 << 20;                 // poll bailout: guarantees termination

#pragma unroll 1
    for (int t = 0; t < 1024; t++) {
        // prefetch x_proj for this step (time-major layout) -- overlaps poll
        float xp0 = b2f(xproj[((long)(t * 8 + g) << 11) + colbase + frm]);
        float xp1 = b2f(xproj[((long)(t * 8 + g) << 11) + colbase + 16 + frm]);

        float s0, s1;
        if (t > 0) {
            if (wv == 0) {
                // wave 0: poll the group's 256 atoms (4/lane, distinct addrs)
                const u64* buf = hx + (g << 9) + (((t - 1) & 1) << 8);
                const u64* p0 = buf + lane;
                const u64* p1 = buf + 64 + lane;
                const u64* p2 = buf + 128 + lane;
                const u64* p3 = buf + 192 + lane;
                u64 v0, v1, v2, v3;
                const unsigned want = (unsigned)t;
                while (true) {
                    if constexpr (L2C) {
                        u64 z = 0;
                        asm volatile(
                            "global_atomic_add_x2 %0, %4, %8, off sc0\n\t"
                            "global_atomic_add_x2 %1, %5, %8, off sc0\n\t"
                            "global_atomic_add_x2 %2, %6, %8, off sc0\n\t"
                            "global_atomic_add_x2 %3, %7, %8, off sc0\n\t"
                            "s_waitcnt vmcnt(0)"
                            : "=&v"(v0), "=&v"(v1), "=&v"(v2), "=&v"(v3)
                            : "v"(p0), "v"(p1), "v"(p2), "v"(p3), "v"(z)
                            : "memory");
                    } else {
                        asm volatile(
                            "global_load_dwordx2 %0, %4, off sc0 sc1\n\t"
                            "global_load_dwordx2 %1, %5, off sc0 sc1\n\t"
                            "global_load_dwordx2 %2, %6, off sc0 sc1\n\t"
                            "global_load_dwordx2 %3, %7, off sc0 sc1\n\t"
                            "s_waitcnt vmcnt(0)"
                            : "=&v"(v0), "=&v"(v1), "=&v"(v2), "=&v"(v3)
                            : "v"(p0), "v"(p1), "v"(p2), "v"(p3)
                            : "memory");
                    }
                    bool ok = ((unsigned)(v0 >> 32) == want) &
                              ((unsigned)(v1 >> 32) == want) &
                              ((unsigned)(v2 >> 32) == want) &
                              ((unsigned)(v3 >> 32) == want);
                    if (__all(ok) || --budget < 0) break;
                }
                hsh[lane]       = (unsigned)v0;
                hsh[64 + lane]  = (unsigned)v1;
                hsh[128 + lane] = (unsigned)v2;
                hsh[192 + lane] = (unsigned)v3;
                __threadfence_block();        // LDS payload before flag
                if (lane == 0)
                    __hip_atomic_store(hflag, t, __ATOMIC_RELAXED,
                                       __HIP_MEMORY_SCOPE_WORKGROUP);
            } else {
                // waves 1-7: spin on LDS flag (no fabric traffic)
                while (__hip_atomic_load(hflag, __ATOMIC_RELAXED,
                                         __HIP_MEMORY_SCOPE_WORKGROUP) < t) {
                    if (--budget < 0) break;
                }
                __threadfence_block();        // flag before payload reads
            }

            f32x4 a0p[4], a1p[4];
#pragma unroll
            for (int r = 0; r < 4; r++) { a0p[r] = zero4(); a1p[r] = zero4(); }
#pragma unroll
            for (int r4 = 0; r4 < 4; r4++) {
                uint4 af[4];
#pragma unroll
                for (int q = 0; q < 4; q++)
                    af[q] = *(const uint4*)&hsh[(((r4 << 2) | q) << 4) + (fq << 2)];
#pragma unroll
                for (int q = 0; q < 4; q++) {
                    a0p[r4] = mfma_bf16(af[q], bfrag[0][(r4 << 2) | q], a0p[r4]);
                    a1p[r4] = mfma_bf16(af[q], bfrag[1][(r4 << 2) | q], a1p[r4]);
                }
            }
            // A-rows are broadcast-identical -> row-0 result valid on ALL lanes
            s0 = (a0p[0][0] + a0p[1][0]) + (a0p[2][0] + a0p[3][0]) + xp0;
            s1 = (a1p[0][0] + a1p[1][0]) + (a1p[2][0] + a1p[3][0]) + xp1;
        } else {
            s0 = xp0;                     // h(-1) = 0
            s1 = xp1;
        }

        // gate gather: lane j (<8) needs cols 4j..4j+3 of this wave's 32 cols.
        // cols 0..15 live in s0 (lane = col&15), 16..31 in s1.
        float ss[4];
#pragma unroll
        for (int k = 0; k < 4; k++) {
            int src = ((lane << 2) + k) & 15;
            float t0 = __shfl(s0, src);
            float t1 = __shfl(s1, src);
            ss[k] = (lane < 4) ? t0 : t1;
        }
        float iv = 1.f / (1.f + __expf(-ss[0]));
        float fv = 1.f / (1.f + __expf(-ss[1]));
        float gv = 1.f - 2.f / (__expf(2.f * ss[2]) + 1.f);
        float ov = 1.f / (1.f + __expf(-ss[3]));
        creg = fv * creg + iv * gv;
        float hv = ov * (1.f - 2.f / (__expf(2.f * creg) + 1.f));
        float hn = __shfl_down(hv, 1);    // neighbor unit's h
        if (lane < 8 && !(lane & 1)) {
            unsigned dw = (unsigned)f2b(hv) | ((unsigned)f2b(hn) << 16);
            int d = (s << 5) + (wv << 2) + (lane >> 1);   // group h dword 0..255
            u64 pv = ((u64)(unsigned)(t + 1) << 32) | (u64)dw;
            u64* dst = &hx[(g << 9) + ((t & 1) << 8) + d];
            if constexpr (L2C) {
                asm volatile("global_atomic_swap_x2 %0, %1, off"
                             :: "v"(dst), "v"(pv) : "memory");
            } else {
                asm volatile("global_store_dwordx2 %0, %1, off sc0 sc1"
                             :: "v"(dst), "v"(pv) : "memory");
            }
            ((unsigned*)h)[(((long)(g * 1024 + t)) << 8) + d] = dw;
        }
    }
}

// ---------------------------------------------------------------------------
// Persistent LSTM recurrence, batch-partitioned: 64 WGs = 8 groups x 8 WGs.
// Group g = bid%8 owns batch g; slice s = bid/8 owns packed gate-cols
// [s*256,+256); wave wv owns 32 cols = units [s*64+wv*8,+8). Weights:
// bfrag[2][16] = 128 VGPRs/lane (proven max). Startup XCD placement check:
// MALL-published XCC_IDs, unanimous verdict. Same-XCD -> L2-atomic fast
// path; else MALL path. Wrong placement degrades speed only.
// ---------------------------------------------------------------------------
__global__ __launch_bounds__(512, 1) void lstm_rec(
    const u16* __restrict__ WhhP, const u16* __restrict__ xproj,
    u16* __restrict__ h, u64* __restrict__ hx, unsigned* __restrict__ xcdid) {
    __shared__ __align__(16) unsigned hshare[256];   // group h payload (dwords)
    __shared__ int hflag;                            // last staged step
    const int bid = blockIdx.x;           // 64
    const int g = bid & 7;                // batch / group
    const int s = bid >> 3;               // gate-col slice 0..7
    const int tid = threadIdx.x;          // 512
    const int lane = tid & 63, wv = tid >> 6;
    const int frm = lane & 15, fq = lane >> 4;
    const int colbase = (s << 8) + (wv << 5);   // global packed gate-col base

    uint4 bfrag[2][16];
#pragma unroll
    for (int T = 0; T < 2; T++)
#pragma unroll
        for (int kk = 0; kk < 16; kk++)
            bfrag[T][kk] = *(const uint4*)&WhhP[((long)(colbase + (T << 4) + frm) << 9) +
                                                (kk << 5) + (fq << 3)];

    // ---- one-time XCD placement check (MALL-coherent, deterministic) ----
    unsigned myxcd;
    asm volatile("s_getreg_b32 %0, hwreg(HW_REG_XCC_ID)" : "=s"(myxcd));
    if (tid == 0) {
        hflag = -1;
        unsigned val = 0x100u | (myxcd & 0xffu);
        asm volatile("global_store_dword %0, %1, off sc0 sc1"
                     :: "v"(&xcdid[bid]), "v"(val) : "memory");
    }
    const unsigned* pid = &xcdid[g + ((lane & 7) << 3)];   // group member g+8j
    unsigned idv = 0;
    int bd = 1 << 22;
    while (true) {
        asm volatile("global_load_dword %0, %1, off sc0 sc1\n\ts_waitcnt vmcnt(0)"
                     : "=&v"(idv) : "v"(pid) : "memory");
        if (__all((idv >> 8) == 1u) || --bd < 0) break;
    }
    bool same = (bd >= 0) && __all((idv & 0xffu) == (__shfl(idv, 0) & 0xffu));
    __syncthreads();                      // hflag init visible to all waves

    if (same)
        lstm_loop<true>(xproj, h, hx, bfrag, hshare, &hflag,
                        g, s, wv, lane, frm, fq, colbase);
    else
        lstm_loop<false>(xproj, h, hx, bfrag, hshare, &hflag,
                         g, s, wv, lane, frm, fq, colbase);
}

// ---------------------------------------------------------------------------
// h [b][t][u] -> hT [b][u][t]
// ---------------------------------------------------------------------------
__global__ __launch_bounds__(256) void transpose_h(const u16* __restrict__ h,
                                                   u16* __restrict__ hT) {
    __shared__ __align__(16) u16 tile[64][72];
    const int b = blockIdx.z;
    const int t0 = blockIdx.x << 6, u0 = blockIdx.y << 6;
    const int tid = threadIdx.x;
    const int r = tid >> 3, c8 = (tid & 7) << 3;
#pragma unroll
    for (int j = 0; j < 2; j++) {
        int row = r + (j << 5);
        *(uint4*)&tile[row][c8] =
            *(const uint4*)&h[(((long)b << 10) + t0 + row) * 512 + u0 + c8];
    }
    __syncthreads();
#pragma unroll
    for (int j = 0; j < 2; j++) {
        int urow = r + (j << 5);
        unsigned wds[4];
#pragma unroll
        for (int k = 0; k < 4; k++) {
            unsigned lo = tile[c8 + (k << 1)][urow];
            unsigned hi = tile[c8 + (k << 1) + 1][urow];
            wds[k] = lo | (hi << 16);
        }
        uint4 v; v.x = wds[0]; v.y = wds[1]; v.z = wds[2]; v.w = wds[3];
        *(uint4*)&hT[(((long)b << 9) + u0 + urow) * 1024 + t0 + c8] = v;
    }
}

// ---------------------------------------------------------------------------
// Masked softmax over rows of scores [8192][1024]; w = softmax*mask (bf16);
// hasnb = 1.0 if any neighbor else 0.0
// ---------------------------------------------------------------------------
__global__ __launch_bounds__(256) void softmax_row(
    const float* __restrict__ scores, const int* __restrict__ adj,
    u16* __restrict__ w, float* __restrict__ hasnb) {
    __shared__ float red[4];
    const int row = blockIdx.x;  // 8192
    const int i = row & 1023;
    const int tid = threadIdx.x;
    const int lane = tid & 63, wave = tid >> 6;
    const float* s = scores + ((long)row << 10);
    const int* arow = adj + ((long)row << 10);

    float sv[4]; bool mk[4];
    float mx = -3.0e38f;
#pragma unroll
    for (int q = 0; q < 4; q++) {
        int j = tid + (q << 8);
        mk[q] = (arow[j] > 0) && (j != i);
        sv[q] = s[j];
        if (mk[q]) mx = fmaxf(mx, sv[q]);
    }
    for (int off = 32; off; off >>= 1) mx = fmaxf(mx, __shfl_xor(mx, off));
    if (lane == 0) red[wave] = mx;
    __syncthreads();
    mx = fmaxf(fmaxf(red[0], red[1]), fmaxf(red[2], red[3]));
    float e[4]; float sum = 0.f;
#pragma unroll
    for (int q = 0; q < 4; q++) {
        e[q] = mk[q] ? __expf(sv[q] - mx) : 0.f;
        sum += e[q];
    }
    __syncthreads();
    for (int off = 32; off; off >>= 1) sum += __shfl_xor(sum, off);
    if (lane == 0) red[wave] = sum;
    __syncthreads();
    sum = red[0] + red[1] + red[2] + red[3];
    float inv = sum > 0.f ? 1.f / sum : 0.f;
#pragma unroll
    for (int q = 0; q < 4; q++) {
        int j = tid + (q << 8);
        w[((long)row << 10) + j] = f2b(e[q] * inv);
    }
    if (tid == 0) hasnb[row] = sum > 0.f ? 1.f : 0.f;
}

// ---------------------------------------------------------------------------
extern "C" void kernel_launch(void* const* d_in, const int* in_sizes, int n_in,
                              void* d_out, int out_size, void* d_ws, size_t ws_size,
                              hipStream_t stream) {
    const float* feats = (const float*)d_in[0];
    const int*   adj   = (const int*)d_in[1];
    const float* W_ih  = (const float*)d_in[2];
    const float* W_hh  = (const float*)d_in[3];
    const float* b_ih  = (const float*)d_in[4];
    const float* b_hh  = (const float*)d_in[5];
    const float* gx_W1 = (const float*)d_in[6];  const float* gx_b1 = (const float*)d_in[7];
    const float* gx_W2 = (const float*)d_in[8];  const float* gx_b2 = (const float*)d_in[9];
    const float* gz_W1 = (const float*)d_in[10]; const float* gz_b1 = (const float*)d_in[11];
    const float* gz_W2 = (const float*)d_in[12]; const float* gz_b2 = (const float*)d_in[13];
    const float* gv_W1 = (const float*)d_in[14]; const float* gv_b1 = (const float*)d_in[15];
    const float* gv_W2 = (const float*)d_in[16]; const float* gv_b2 = (const float*)d_in[17];
    const float* gn_W1 = (const float*)d_in[18]; const float* gn_b1 = (const float*)d_in[19];
    const float* gn_W2 = (const float*)d_in[20]; const float* gn_b2 = (const float*)d_in[21];
    const float* out_W = (const float*)d_in[22]; const float* out_b = (const float*)d_in[23];

    char* ws = (char*)d_ws;
    size_t off = 0;
    auto alloc = [&](size_t bytes) {
        void* p = ws + off;
        off += (bytes + 255) & ~(size_t)255;
        return p;
    };
    u16* WhhP      = (u16*)alloc(2048L * 512 * 2);
    u16* WihP      = (u16*)alloc(2048L * 256 * 2);
    float* biasP   = (float*)alloc(2048L * 4);
    u64* hx        = (u64*)alloc(8L * 512 * 8);
    unsigned* xcdid = (unsigned*)alloc(64L * 4);
    u16* featsB    = (u16*)alloc(8192L * 256 * 2);
    // W1 pair adjacent (stacked-N GEMM reads them as one [512][512] B):
    u16* gxW1b     = (u16*)alloc(256L * 512 * 2);
    u16* gvW1b     = (u16*)alloc(256L * 512 * 2);
    // W2 pair adjacent (batched bz=2 GEMM, sBb = 256*256):
    u16* gxW2b     = (u16*)alloc(256L * 256 * 2);
    u16* gvW2b     = (u16*)alloc(256L * 256 * 2);
    u16* gzW1b     = (u16*)alloc(256L * 512 * 2);
    u16* gzW2b     = (u16*)alloc(256L * 256 * 2);
    u16* gnW1b     = (u16*)alloc(256L * 256 * 2);
    u16* gnW2b     = (u16*)alloc(256L * 256 * 2);
    u16* outWb     = (u16*)alloc(256L * 768 * 2);
    float* b1cat   = (float*)alloc(512L * 4);   // [gx_b1; gv_b1]
    float* b2cat   = (float*)alloc(512L * 4);   // [gx_b2; gv_b2]
    u16* xproj     = (u16*)alloc(8L * 1024 * 2048 * 2);
    u16* h         = (u16*)alloc(8L * 1024 * 512 * 2);
    u16* hT        = (u16*)alloc(8L * 1024 * 512 * 2);
    // ax/av adjacent (batched C, sCb = 8192*256):
    u16* ax        = (u16*)alloc(8192L * 256 * 2);
    u16* av        = (u16*)alloc(8192L * 256 * 2);
    u16* agg       = (u16*)alloc(8192L * 256 * 2);
    float* hasnb   = (float*)alloc(8192L * 4);
    float* scores  = (float*)alloc(8L * 1024 * 1024 * 4);
    u16* w         = (u16*)alloc(8L * 1024 * 1024 * 2);
    if (off > ws_size) return;  // workspace too small -> fail visibly

    // Temp aliasing into `scores` (32MB) -- all uses are time-disjoint:
    //  t1cat (8MB, [8192][512] bf16): written/read BEFORE scores GEMM.
    //  tA/tB (4MB each): gz/gn chain temps, used AFTER softmax consumed scores.
    u16* t1cat = (u16*)scores;
    u16* tA    = (u16*)scores;
    u16* tB    = (u16*)((char*)scores + (8192L * 256 * 2));

    (void)hipMemsetAsync(hx, 0, 8L * 512 * 8, stream);    // deterministic tags
    (void)hipMemsetAsync(xcdid, 0, 64L * 4, stream);      // placement slots
    pack_params<<<2048, 256, 0, stream>>>(W_hh, W_ih, b_ih, b_hh, WhhP, WihP, biasP);
    bias_pack<<<1, 512, 0, stream>>>(gx_b1, gv_b1, gx_b2, gv_b2, b1cat, b2cat);

    // single fused f32->bf16 conversion launch for all 10 buffers
    CvtJobs J{};
    int nb = 0, ji = 0;
    auto addjob = [&](const float* s, u16* d, int n) {
        J.src[ji] = s; J.dst[ji] = d; J.n[ji] = n; J.off[ji] = nb;
        nb += (n + 1023) >> 10; ji++;
    };
    addjob(feats, featsB, 8192 * 256);
    addjob(gx_W1, gxW1b, 256 * 512);  addjob(gv_W1, gvW1b, 256 * 512);
    addjob(gx_W2, gxW2b, 256 * 256);  addjob(gv_W2, gvW2b, 256 * 256);
    addjob(gz_W1, gzW1b, 256 * 512);  addjob(gz_W2, gzW2b, 256 * 256);
    addjob(gn_W1, gnW1b, 256 * 256);  addjob(gn_W2, gnW2b, 256 * 256);
    addjob(out_W, outWb, 256 * 768);
    J.cnt = ji;
    cvt_multi<<<nb, 256, 0, stream>>>(J);

    // x_proj = feats @ W_ihP^T + (b_ih+b_hh), stored time-major [t][b][p]
    gemm_bt<<<dim3(128, 16, 1), 256, 0, stream>>>(
        featsB, nullptr, 256, WihP, xproj, 8192, 2048, 256, 0, 0, 0,
        biasP, nullptr, GF_XPOSE);

    lstm_rec<<<64, 512, 0, stream>>>(WhhP, xproj, h, hx, xcdid);

    transpose_h<<<dim3(16, 8, 8), 256, 0, stream>>>(h, hT);

    // t1cat = relu(h @ [gxW1;gvW1]^T + [gx_b1;gv_b1])  [8192][512], one GEMM
    gemm_bt<<<dim3(128, 4, 1), 256, 0, stream>>>(
        h, nullptr, 512, gxW1b, t1cat, 8192, 512, 512, 0, 0, 0,
        b1cat, nullptr, GF_RELU);
    // ax|av = batched: bz=0 reads t1cat[:,0:256]@gxW2^T, bz=1 t1cat[:,256:]@gvW2^T
    gemm_bt<<<dim3(128, 2, 2), 256, 0, stream>>>(
        t1cat, nullptr, 512 /*row stride*/, gxW2b, ax, 8192, 256, 256,
        256 /*sAb: col offset*/, 65536 /*sBb*/, 8192L * 256 /*sCb*/,
        b2cat, nullptr, GF_BIASB);

    // scores[b] = ax[b] @ av[b]^T  (f32)
    gemm_bt<<<dim3(16, 8, 8), 256, 0, stream>>>(
        ax, nullptr, 256, av, scores, 1024, 1024, 256,
        262144, 262144, 1048576, nullptr, nullptr, GF_F32);

    softmax_row<<<8192, 256, 0, stream>>>(scores, adj, w, hasnb);

    // sagg[b] = w[b] @ h[b]  via A=w, B=hT (B^T form); xproj is dead -> reuse
    u16* sagg = xproj;
    gemm_bt<<<dim3(16, 4, 8), 256, 0, stream>>>(
        w, nullptr, 1024, hT, sagg, 1024, 512, 1024,
        1048576, 524288, 524288, nullptr, nullptr, 0);

    // agg = mlp(mlp(sagg; gz); gn) * hasnb   (temps alias dead scores region)
    gemm_bt<<<dim3(128, 2, 1), 256, 0, stream>>>(
        sagg, nullptr, 512, gzW1b, tA, 8192, 256, 512, 0, 0, 0, gz_b1, nullptr, GF_RELU);
    gemm_bt<<<dim3(128, 2, 1), 256, 0, stream>>>(
        tA, nullptr, 256, gzW2b, tB, 8192, 256, 256, 0, 0, 0, gz_b2, nullptr, 0);
    gemm_bt<<<dim3(128, 2, 1), 256, 0, stream>>>(
        tB, nullptr, 256, gnW1b, tA, 8192, 256, 256, 0, 0, 0, gn_b1, nullptr, GF_RELU);
    gemm_bt<<<dim3(128, 2, 1), 256, 0, stream>>>(
        tA, nullptr, 256, gnW2b, agg, 8192, 256, 256, 0, 0, 0, gn_b2, hasnb, 0);

    // out = concat(h, agg) @ out_W^T + out_b  (f32 output)
    gemm_bt<<<dim3(128, 2, 1), 256, 0, stream>>>(
        h, agg, 512, outWb, (float*)d_out, 8192, 256, 768, 0, 0, 0, out_b, nullptr, GF_F32);
}